// Round 1
// baseline (302.171 us; speedup 1.0000x reference)
//
#include <hip/hip_runtime.h>

// Problem constants (from reference)
#define DIM_IN   2048
#define FEAT     128
#define KP1      16385      // NCE_N + 1
#define NDATA    100000
#define BATCH    64
#define RT       256        // rows per gemm tile
#define KC       32         // k per staging pass (4 passes of 32 = 128)
#define NTILES   ((NDATA + RT - 1) / RT)   // 391
#define GCH      16         // k-chunks per (side,b) in gather kernel

constexpr float NCE_T_INV = 1.0f / 0.07f;
constexpr float M_CONST   = 16384.0f / 100000.0f;   // NCE_N / N_DATA
constexpr float EPS_C     = 1e-7f;

// ---------------------------------------------------------------------------
// Kernel 1: h = l2norm(feat @ w.T + b). Per-wave coalesced row dots.
// Block 0 additionally zeroes z[128] and out (replaces two hipMemsetAsync
// graph nodes; stream order guarantees this lands before gather/loss).
// ---------------------------------------------------------------------------
__global__ void __launch_bounds__(256) embed_kernel(
    const float* __restrict__ feat_s, const float* __restrict__ feat_t,
    const float* __restrict__ w_s, const float* __restrict__ b_s,
    const float* __restrict__ w_t, const float* __restrict__ b_t,
    float* __restrict__ v_out, float* __restrict__ z_zero,
    float* __restrict__ out_zero)
{
    const int blk  = blockIdx.x;      // side*64 + b
    const int side = blk >> 6;
    const int b    = blk & 63;
    const float* feat = (side == 0 ? feat_s : feat_t) + (size_t)b * DIM_IN;
    const float* w    = (side == 0 ? w_s : w_t);
    const float* bias = (side == 0 ? b_s : b_t);

    __shared__ float sfeat[DIM_IN];
    __shared__ float pre[FEAT];
    __shared__ float wsum[2];

    const int t = threadIdx.x;
    if (blk == 0) {                   // fold the memsets into this launch
        if (t < 128) z_zero[t] = 0.f;
        else if (t == 128) out_zero[0] = 0.f;
    }
    {   // coalesced float4 stage of the feat row (8 KB)
        const float4* f4 = (const float4*)feat;
        float4* s4 = (float4*)sfeat;
        for (int j = t; j < DIM_IN / 4; j += 256) s4[j] = f4[j];
    }
    __syncthreads();

    const int wv = t >> 6, ln = t & 63;
    const float4* w4  = (const float4*)w;
    const float4* sf4 = (const float4*)sfeat;
    for (int d = wv; d < FEAT; d += 4) {
        float s = 0.f;
#pragma unroll
        for (int seg = 0; seg < 8; ++seg) {      // 512 float4 per row / 64 lanes
            float4 a = w4[d * (DIM_IN / 4) + seg * 64 + ln];
            float4 f = sf4[seg * 64 + ln];
            s += a.x * f.x + a.y * f.y + a.z * f.z + a.w * f.w;
        }
#pragma unroll
        for (int o = 32; o > 0; o >>= 1) s += __shfl_xor(s, o, 64);
        if (ln == 0) pre[d] = s;
    }
    __syncthreads();

    if (t < 128) {
        float p = pre[t] + bias[t];
        pre[t] = p;
        float sq = p * p;
#pragma unroll
        for (int o = 32; o > 0; o >>= 1) sq += __shfl_xor(sq, o, 64);
        if ((t & 63) == 0) wsum[t >> 6] = sq;
    }
    __syncthreads();
    if (t < 128) {
        float inv_norm = 1.0f / sqrtf(wsum[0] + wsum[1]);
        v_out[(size_t)blk * FEAT + t] = pre[t] * inv_norm;
    }
}

// ---------------------------------------------------------------------------
// Kernel 2 (REWORKED): dense skinny GEMM + exp. E[sb][n] = exp(dot/T).
// Changes vs previous version (latency/occupancy-bound at 13% occ, 35% VALU):
//  - K split into FOUR passes of 32: sA 32 KB + sB 8 KB = 40 KB LDS
//    -> 4 blocks/CU (was 2 @ 80 KB). All 782 blocks ~co-resident; inter-block
//    TLP covers staging latency + barrier drains.
//  - A staged with global_load_lds (16B): no VGPR round-trip. LDS dest is
//    LINEAR (wave base + lane*16); the XOR swizzle is applied to the GLOBAL
//    source address (f_glob = f_store ^ ((row>>3)&7)) and undone on read
//    (both-sides-or-neither rule). Compute read: 8 rg-values x xor -> 8
//    distinct bank-quads = all 32 banks, conflict-free.
//  - sB reads 2-way aliased (free); thread tile stays 8 rows x 8 anchors.
// ---------------------------------------------------------------------------
__global__ void __launch_bounds__(256, 4) gemm_exp_kernel(
    const float* __restrict__ mem_v1, const float* __restrict__ mem_v2,
    const float* __restrict__ v_in, float* __restrict__ E)
{
    __shared__ __align__(16) float sA[RT * KC];   // 32 KB, [row][f^((row>>3)&7)]
    __shared__ __align__(16) float sB[KC * 64];   // 8 KB,  [k][b]

    const int bx   = blockIdx.x;
    const int side = bx & 1;
    const int tile = bx >> 1;
    const int n0   = tile * RT;
    const float* bank = (side == 0 ? mem_v2 : mem_v1);
    const float* vb   = v_in + (size_t)side * 64 * FEAT;
    const int t  = threadIdx.x;
    const int ag = t & 7;             // anchor group: anchors ag*8..+7
    const int rg = t >> 3;            // row group:    rows n0+rg*8..+7
    const int r0 = n0 + rg * 8;

    const int wv   = t >> 6, ln = t & 63;
    const int rsub = ln >> 3;         // row within 8-row wave segment
    const int fst  = ln & 7;          // float4 slot in LDS row (linear dest)

    float acc[8][8];
#pragma unroll
    for (int i = 0; i < 8; ++i)
#pragma unroll
        for (int j = 0; j < 8; ++j) acc[i][j] = 0.f;

#pragma unroll 1
    for (int kp = 0; kp < 4; ++kp) {
        if (kp) __syncthreads();      // previous pass compute done before restage
        // stage A: async DMA, per wave 8 calls x 8 rows x 128 B.
        // LDS linear: lane l -> sA row (base + l/8), slot l&7.
        // Global source pre-swizzled so read-side XOR recovers column c.
#pragma unroll
        for (int j = 0; j < 8; ++j) {
            const int rl = wv * 64 + j * 8 + rsub;       // tile-local row
            int row = n0 + rl; if (row > NDATA - 1) row = NDATA - 1;
            const int fg = fst ^ ((rl >> 3) & 7);
            const float* src = bank + (size_t)row * FEAT + kp * KC + fg * 4;
            float* dst = &sA[(wv * 64 + j * 8) * KC];    // wave-uniform base
            __builtin_amdgcn_global_load_lds(
                (const __attribute__((address_space(1))) void*)src,
                (__attribute__((address_space(3))) void*)dst, 16, 0, 0);
        }
        // stage B: sB[k][b] = v[b][kp*32+k]; scalar writes bank=b -> conflict-free
#pragma unroll
        for (int it = 0; it < 2; ++it) {
            const int i  = t + it * 256;                 // 0..511
            const int b2 = i & 63;
            const int f  = i >> 6;                       // 0..7
            float4 v4 = *(const float4*)(vb + (size_t)b2 * FEAT + kp * KC + f * 4);
            sB[(f * 4 + 0) * 64 + b2] = v4.x;
            sB[(f * 4 + 1) * 64 + b2] = v4.y;
            sB[(f * 4 + 2) * 64 + b2] = v4.z;
            sB[(f * 4 + 3) * 64 + b2] = v4.w;
        }
        __syncthreads();              // drains vmcnt (async A) + lgkmcnt (B)

#pragma unroll 1
        for (int c = 0; c < 8; ++c) {            // 8 chunks of 4 k
            float4 af[8], bf[8];
            const int ca = 4 * ((c ^ (rg & 7)) & 7);     // un-swizzle
#pragma unroll
            for (int i = 0; i < 8; ++i)
                af[i] = *(const float4*)&sA[(rg * 8 + i) * KC + ca];
#pragma unroll
            for (int kk = 0; kk < 4; ++kk) {
                bf[kk * 2 + 0] = *(const float4*)&sB[(c * 4 + kk) * 64 + ag * 8];
                bf[kk * 2 + 1] = *(const float4*)&sB[(c * 4 + kk) * 64 + ag * 8 + 4];
            }
#pragma unroll
            for (int kk = 0; kk < 4; ++kk) {
#pragma unroll
                for (int i = 0; i < 8; ++i) {
                    const float a = (kk == 0) ? af[i].x : (kk == 1) ? af[i].y
                                  : (kk == 2) ? af[i].z : af[i].w;
                    acc[i][0] += a * bf[kk * 2].x;
                    acc[i][1] += a * bf[kk * 2].y;
                    acc[i][2] += a * bf[kk * 2].z;
                    acc[i][3] += a * bf[kk * 2].w;
                    acc[i][4] += a * bf[kk * 2 + 1].x;
                    acc[i][5] += a * bf[kk * 2 + 1].y;
                    acc[i][6] += a * bf[kk * 2 + 1].z;
                    acc[i][7] += a * bf[kk * 2 + 1].w;
                }
            }
        }
    }

    // epilogue: exp + store E[sb][n]; per anchor a wave's 8 same-ag lanes
    // cover 64 consecutive n (coalesced 256 B).
    if (r0 + 8 <= NDATA) {
#pragma unroll
        for (int j = 0; j < 8; ++j) {
            float4 o0, o1;
            o0.x = __expf(acc[0][j] * NCE_T_INV);
            o0.y = __expf(acc[1][j] * NCE_T_INV);
            o0.z = __expf(acc[2][j] * NCE_T_INV);
            o0.w = __expf(acc[3][j] * NCE_T_INV);
            o1.x = __expf(acc[4][j] * NCE_T_INV);
            o1.y = __expf(acc[5][j] * NCE_T_INV);
            o1.z = __expf(acc[6][j] * NCE_T_INV);
            o1.w = __expf(acc[7][j] * NCE_T_INV);
            float* dst = E + (size_t)(side * 64 + ag * 8 + j) * NDATA + r0;
            *(float4*)dst = o0;
            *(float4*)(dst + 4) = o1;
        }
    }
}

// ---------------------------------------------------------------------------
// Kernel 3: gather ex = E[sb][idx[b,k]], store compact, accumulate Z[sb].
// GCH 8 -> 16: latency-bound random 4B reads; double the waves in flight
// (32 waves/CU). blk&127 = sb keeps a given sb's chunks on one XCD.
// ---------------------------------------------------------------------------
__global__ void __launch_bounds__(256) gather_z_kernel(
    const int* __restrict__ sample_idx, const float* __restrict__ E,
    float* __restrict__ ex_out, float* __restrict__ z_out)
{
    const int blk   = blockIdx.x;
    const int chunk = blk >> 7;          // 0..GCH-1
    const int sb    = blk & 127;         // side*64 + b
    const int b     = sb & 63;
    const float* Eb = E + (size_t)sb * NDATA;

    float zp = 0.f;
    for (int k = chunk * 256 + threadIdx.x; k < KP1; k += GCH * 256) {
        const int idx = sample_idx[(size_t)b * KP1 + k];
        const float e = Eb[idx];
        ex_out[(size_t)sb * KP1 + k] = e;
        zp += e;
    }
#pragma unroll
    for (int o = 32; o > 0; o >>= 1) zp += __shfl_xor(zp, o, 64);
    __shared__ float zw[4];
    if ((threadIdx.x & 63) == 0) zw[threadIdx.x >> 6] = zp;
    __syncthreads();
    if (threadIdx.x == 0) atomicAdd(&z_out[sb], zw[0] + zw[1] + zw[2] + zw[3]);
}

// ---------------------------------------------------------------------------
// Kernel 4: loss. 256 blocks (2 chunks x 128 sb). Z summed in-kernel from
// the 64 per-sb partials of this side; 256 output atomics total.
// ---------------------------------------------------------------------------
__global__ void __launch_bounds__(256) loss_kernel(
    const float* __restrict__ ex_in, const float* __restrict__ z_in,
    float* __restrict__ out)
{
    const int blk   = blockIdx.x;
    const int chunk = blk >> 7;          // 0..1
    const int sb    = blk & 127;
    const int side  = sb >> 6;

    __shared__ float zsh;
    if (threadIdx.x < 64) {
        float zv = z_in[side * 64 + threadIdx.x];
#pragma unroll
        for (int o = 32; o > 0; o >>= 1) zv += __shfl_xor(zv, o, 64);
        if (threadIdx.x == 0) zsh = zv;
    }
    __syncthreads();

    const float z  = zsh * ((float)NDATA / (64.0f * (float)KP1));
    const float rz = 1.0f / z;
    const float* ex = ex_in + (size_t)sb * KP1;

    float part = 0.f;
    for (int k = chunk * 256 + threadIdx.x; k < KP1; k += 512) {
        const float x = ex[k] * rz;
        if (k == 0) part += __logf(x / (x + M_CONST + EPS_C));
        else        part += __logf(M_CONST / (x + M_CONST + EPS_C));
    }
#pragma unroll
    for (int o = 32; o > 0; o >>= 1) part += __shfl_xor(part, o, 64);
    __shared__ float pw[4];
    if ((threadIdx.x & 63) == 0) pw[threadIdx.x >> 6] = part;
    __syncthreads();
    if (threadIdx.x == 0)
        atomicAdd(out, -(pw[0] + pw[1] + pw[2] + pw[3]) * (1.0f / 64.0f));
}

// ---------------------------------------------------------------------------
extern "C" void kernel_launch(void* const* d_in, const int* in_sizes, int n_in,
                              void* d_out, int out_size, void* d_ws, size_t ws_size,
                              hipStream_t stream)
{
    const float* feat_s     = (const float*)d_in[0];
    const float* feat_t     = (const float*)d_in[1];
    /* d_in[2] = idx, unused: sample_idx[:,0] already holds it */
    const int*   sample_idx = (const int*)  d_in[3];
    const float* w_s        = (const float*)d_in[4];
    const float* b_s        = (const float*)d_in[5];
    const float* w_t        = (const float*)d_in[6];
    const float* b_t        = (const float*)d_in[7];
    const float* mem_v1     = (const float*)d_in[8];
    const float* mem_v2     = (const float*)d_in[9];
    float* out = (float*)d_out;

    // Workspace layout:
    //   [z: 128 f32 = 512 B]
    //   [v: 2*64*128 f32 = 64 KB]
    //   [ex: 2*64*16385 f32 = 8.39 MB]
    //   [E: 128*100000 f32 = 51.2 MB]  (transposed: E[sb][n])
    char*  ws    = (char*)d_ws;
    float* ws_z  = (float*)ws;
    float* ws_v  = (float*)(ws + 512);
    float* ws_ex = (float*)(ws + 512 + 2 * BATCH * FEAT * sizeof(float));
    float* ws_E  = (float*)(ws + 512 + 2 * BATCH * FEAT * sizeof(float)
                               + (size_t)2 * BATCH * KP1 * sizeof(float));

    // z/out zeroing folded into embed_kernel block 0 (saves 2 graph nodes)
    embed_kernel<<<2 * BATCH, 256, 0, stream>>>(feat_s, feat_t, w_s, b_s, w_t, b_t,
                                                ws_v, ws_z, out);
    gemm_exp_kernel<<<2 * NTILES, 256, 0, stream>>>(mem_v1, mem_v2, ws_v, ws_E);
    gather_z_kernel<<<2 * BATCH * GCH, 256, 0, stream>>>(sample_idx, ws_E, ws_ex, ws_z);
    loss_kernel<<<2 * BATCH * 2, 256, 0, stream>>>(ws_ex, ws_z, out);
}

// Round 2
// 263.415 us; speedup vs baseline: 1.1471x; 1.1471x over previous
//
#include <hip/hip_runtime.h>

// Problem constants (from reference)
#define DIM_IN   2048
#define FEAT     128
#define KP1      16385      // NCE_N + 1
#define NDATA    100000
#define BATCH    64
#define RT       256        // rows per gemm tile
#define KC       32         // k per staging pass (4 passes of 32 = 128)
#define NTILES   ((NDATA + RT - 1) / RT)   // 391
#define GCH      16         // k-chunks per (side,b) in gather kernel

constexpr float NCE_T_INV = 1.0f / 0.07f;
constexpr float M_CONST   = 16384.0f / 100000.0f;   // NCE_N / N_DATA
constexpr float EPS_C     = 1e-7f;

// ---------------------------------------------------------------------------
// Kernel 1: h = l2norm(feat @ w.T + b). Per-wave coalesced row dots.
// Block 0 additionally zeroes z[128] and out (replaces two hipMemsetAsync
// graph nodes; stream order guarantees this lands before gather/loss).
// ---------------------------------------------------------------------------
__global__ void __launch_bounds__(256) embed_kernel(
    const float* __restrict__ feat_s, const float* __restrict__ feat_t,
    const float* __restrict__ w_s, const float* __restrict__ b_s,
    const float* __restrict__ w_t, const float* __restrict__ b_t,
    float* __restrict__ v_out, float* __restrict__ z_zero,
    float* __restrict__ out_zero)
{
    const int blk  = blockIdx.x;      // side*64 + b
    const int side = blk >> 6;
    const int b    = blk & 63;
    const float* feat = (side == 0 ? feat_s : feat_t) + (size_t)b * DIM_IN;
    const float* w    = (side == 0 ? w_s : w_t);
    const float* bias = (side == 0 ? b_s : b_t);

    __shared__ float sfeat[DIM_IN];
    __shared__ float pre[FEAT];
    __shared__ float wsum[2];

    const int t = threadIdx.x;
    if (blk == 0) {                   // fold the memsets into this launch
        if (t < 128) z_zero[t] = 0.f;
        else if (t == 128) out_zero[0] = 0.f;
    }
    {   // coalesced float4 stage of the feat row (8 KB)
        const float4* f4 = (const float4*)feat;
        float4* s4 = (float4*)sfeat;
        for (int j = t; j < DIM_IN / 4; j += 256) s4[j] = f4[j];
    }
    __syncthreads();

    const int wv = t >> 6, ln = t & 63;
    const float4* w4  = (const float4*)w;
    const float4* sf4 = (const float4*)sfeat;
    for (int d = wv; d < FEAT; d += 4) {
        float s = 0.f;
#pragma unroll
        for (int seg = 0; seg < 8; ++seg) {      // 512 float4 per row / 64 lanes
            float4 a = w4[d * (DIM_IN / 4) + seg * 64 + ln];
            float4 f = sf4[seg * 64 + ln];
            s += a.x * f.x + a.y * f.y + a.z * f.z + a.w * f.w;
        }
#pragma unroll
        for (int o = 32; o > 0; o >>= 1) s += __shfl_xor(s, o, 64);
        if (ln == 0) pre[d] = s;
    }
    __syncthreads();

    if (t < 128) {
        float p = pre[t] + bias[t];
        pre[t] = p;
        float sq = p * p;
#pragma unroll
        for (int o = 32; o > 0; o >>= 1) sq += __shfl_xor(sq, o, 64);
        if ((t & 63) == 0) wsum[t >> 6] = sq;
    }
    __syncthreads();
    if (t < 128) {
        float inv_norm = 1.0f / sqrtf(wsum[0] + wsum[1]);
        v_out[(size_t)blk * FEAT + t] = pre[t] * inv_norm;
    }
}

// ---------------------------------------------------------------------------
// Kernel 2: dense skinny GEMM + exp. E[sb][n] = exp(dot/T).
// Round-1 post-mortem: __launch_bounds__(256,4) over-squeezed the allocator
// to 64 VGPRs (acc[8][8] alone is 64) -> scratch spill: +83 MB writes,
// +74 MB fetch per dispatch, VALUBusy 23%. FIX: back to (256,2) which this
// inner loop empirically compiles to ~112 VGPRs (round 0) -> no spill, and
// 112 VGPR still admits 4 waves/SIMD; LDS 40 KB admits 4 blocks/CU.
// Kept from round 1 (verified correct, bank-conflict-free):
//  - K split into FOUR passes of 32: sA 32 KB + sB 8 KB = 40 KB LDS.
//  - A staged with global_load_lds (16B): linear LDS dest (wave base +
//    lane*16); XOR swizzle applied to the GLOBAL source address and undone
//    on read (both-sides-or-neither rule). Read: 8 rg-values x xor ->
//    8 distinct bank-quads = all 32 banks, conflict-free (measured 0).
//  - sB reads 2-way aliased (free); thread tile 8 rows x 8 anchors.
// ---------------------------------------------------------------------------
__global__ void __launch_bounds__(256, 2) gemm_exp_kernel(
    const float* __restrict__ mem_v1, const float* __restrict__ mem_v2,
    const float* __restrict__ v_in, float* __restrict__ E)
{
    __shared__ __align__(16) float sA[RT * KC];   // 32 KB, [row][f^((row>>3)&7)]
    __shared__ __align__(16) float sB[KC * 64];   // 8 KB,  [k][b]

    const int bx   = blockIdx.x;
    const int side = bx & 1;
    const int tile = bx >> 1;
    const int n0   = tile * RT;
    const float* bank = (side == 0 ? mem_v2 : mem_v1);
    const float* vb   = v_in + (size_t)side * 64 * FEAT;
    const int t  = threadIdx.x;
    const int ag = t & 7;             // anchor group: anchors ag*8..+7
    const int rg = t >> 3;            // row group:    rows n0+rg*8..+7
    const int r0 = n0 + rg * 8;

    const int wv   = t >> 6, ln = t & 63;
    const int rsub = ln >> 3;         // row within 8-row wave segment
    const int fst  = ln & 7;          // float4 slot in LDS row (linear dest)

    float acc[8][8];
#pragma unroll
    for (int i = 0; i < 8; ++i)
#pragma unroll
        for (int j = 0; j < 8; ++j) acc[i][j] = 0.f;

#pragma unroll 1
    for (int kp = 0; kp < 4; ++kp) {
        if (kp) __syncthreads();      // previous pass compute done before restage
        // stage A: async DMA, per wave 8 calls x 8 rows x 128 B.
        // LDS linear: lane l -> sA row (base + l/8), slot l&7.
        // Global source pre-swizzled so read-side XOR recovers column c.
#pragma unroll
        for (int j = 0; j < 8; ++j) {
            const int rl = wv * 64 + j * 8 + rsub;       // tile-local row
            int row = n0 + rl; if (row > NDATA - 1) row = NDATA - 1;
            const int fg = fst ^ ((rl >> 3) & 7);
            const float* src = bank + (size_t)row * FEAT + kp * KC + fg * 4;
            float* dst = &sA[(wv * 64 + j * 8) * KC];    // wave-uniform base
            __builtin_amdgcn_global_load_lds(
                (const __attribute__((address_space(1))) void*)src,
                (__attribute__((address_space(3))) void*)dst, 16, 0, 0);
        }
        // stage B: sB[k][b] = v[b][kp*32+k]; scalar writes bank=b -> conflict-free
#pragma unroll
        for (int it = 0; it < 2; ++it) {
            const int i  = t + it * 256;                 // 0..511
            const int b2 = i & 63;
            const int f  = i >> 6;                       // 0..7
            float4 v4 = *(const float4*)(vb + (size_t)b2 * FEAT + kp * KC + f * 4);
            sB[(f * 4 + 0) * 64 + b2] = v4.x;
            sB[(f * 4 + 1) * 64 + b2] = v4.y;
            sB[(f * 4 + 2) * 64 + b2] = v4.z;
            sB[(f * 4 + 3) * 64 + b2] = v4.w;
        }
        __syncthreads();              // drains vmcnt (async A) + lgkmcnt (B)

#pragma unroll 1
        for (int c = 0; c < 8; ++c) {            // 8 chunks of 4 k
            float4 af[8], bf[8];
            const int ca = 4 * ((c ^ (rg & 7)) & 7);     // un-swizzle
#pragma unroll
            for (int i = 0; i < 8; ++i)
                af[i] = *(const float4*)&sA[(rg * 8 + i) * KC + ca];
#pragma unroll
            for (int kk = 0; kk < 4; ++kk) {
                bf[kk * 2 + 0] = *(const float4*)&sB[(c * 4 + kk) * 64 + ag * 8];
                bf[kk * 2 + 1] = *(const float4*)&sB[(c * 4 + kk) * 64 + ag * 8 + 4];
            }
#pragma unroll
            for (int kk = 0; kk < 4; ++kk) {
#pragma unroll
                for (int i = 0; i < 8; ++i) {
                    const float a = (kk == 0) ? af[i].x : (kk == 1) ? af[i].y
                                  : (kk == 2) ? af[i].z : af[i].w;
                    acc[i][0] += a * bf[kk * 2].x;
                    acc[i][1] += a * bf[kk * 2].y;
                    acc[i][2] += a * bf[kk * 2].z;
                    acc[i][3] += a * bf[kk * 2].w;
                    acc[i][4] += a * bf[kk * 2 + 1].x;
                    acc[i][5] += a * bf[kk * 2 + 1].y;
                    acc[i][6] += a * bf[kk * 2 + 1].z;
                    acc[i][7] += a * bf[kk * 2 + 1].w;
                }
            }
        }
    }

    // epilogue: exp + store E[sb][n]; per anchor a wave's 8 same-ag lanes
    // cover 64 consecutive n (coalesced 256 B).
    if (r0 + 8 <= NDATA) {
#pragma unroll
        for (int j = 0; j < 8; ++j) {
            float4 o0, o1;
            o0.x = __expf(acc[0][j] * NCE_T_INV);
            o0.y = __expf(acc[1][j] * NCE_T_INV);
            o0.z = __expf(acc[2][j] * NCE_T_INV);
            o0.w = __expf(acc[3][j] * NCE_T_INV);
            o1.x = __expf(acc[4][j] * NCE_T_INV);
            o1.y = __expf(acc[5][j] * NCE_T_INV);
            o1.z = __expf(acc[6][j] * NCE_T_INV);
            o1.w = __expf(acc[7][j] * NCE_T_INV);
            float* dst = E + (size_t)(side * 64 + ag * 8 + j) * NDATA + r0;
            *(float4*)dst = o0;
            *(float4*)(dst + 4) = o1;
        }
    }
}

// ---------------------------------------------------------------------------
// Kernel 3: gather ex = E[sb][idx[b,k]], store compact, accumulate Z[sb].
// GCH=16: latency-bound random 4B reads; 32 waves in flight per CU.
// blk&127 = sb keeps a given sb's chunks on one XCD.
// ---------------------------------------------------------------------------
__global__ void __launch_bounds__(256) gather_z_kernel(
    const int* __restrict__ sample_idx, const float* __restrict__ E,
    float* __restrict__ ex_out, float* __restrict__ z_out)
{
    const int blk   = blockIdx.x;
    const int chunk = blk >> 7;          // 0..GCH-1
    const int sb    = blk & 127;         // side*64 + b
    const int b     = sb & 63;
    const float* Eb = E + (size_t)sb * NDATA;

    float zp = 0.f;
    for (int k = chunk * 256 + threadIdx.x; k < KP1; k += GCH * 256) {
        const int idx = sample_idx[(size_t)b * KP1 + k];
        const float e = Eb[idx];
        ex_out[(size_t)sb * KP1 + k] = e;
        zp += e;
    }
#pragma unroll
    for (int o = 32; o > 0; o >>= 1) zp += __shfl_xor(zp, o, 64);
    __shared__ float zw[4];
    if ((threadIdx.x & 63) == 0) zw[threadIdx.x >> 6] = zp;
    __syncthreads();
    if (threadIdx.x == 0) atomicAdd(&z_out[sb], zw[0] + zw[1] + zw[2] + zw[3]);
}

// ---------------------------------------------------------------------------
// Kernel 4: loss. 256 blocks (2 chunks x 128 sb). Z summed in-kernel from
// the 64 per-sb partials of this side; 256 output atomics total.
// ---------------------------------------------------------------------------
__global__ void __launch_bounds__(256) loss_kernel(
    const float* __restrict__ ex_in, const float* __restrict__ z_in,
    float* __restrict__ out)
{
    const int blk   = blockIdx.x;
    const int chunk = blk >> 7;          // 0..1
    const int sb    = blk & 127;
    const int side  = sb >> 6;

    __shared__ float zsh;
    if (threadIdx.x < 64) {
        float zv = z_in[side * 64 + threadIdx.x];
#pragma unroll
        for (int o = 32; o > 0; o >>= 1) zv += __shfl_xor(zv, o, 64);
        if (threadIdx.x == 0) zsh = zv;
    }
    __syncthreads();

    const float z  = zsh * ((float)NDATA / (64.0f * (float)KP1));
    const float rz = 1.0f / z;
    const float* ex = ex_in + (size_t)sb * KP1;

    float part = 0.f;
    for (int k = chunk * 256 + threadIdx.x; k < KP1; k += 512) {
        const float x = ex[k] * rz;
        if (k == 0) part += __logf(x / (x + M_CONST + EPS_C));
        else        part += __logf(M_CONST / (x + M_CONST + EPS_C));
    }
#pragma unroll
    for (int o = 32; o > 0; o >>= 1) part += __shfl_xor(part, o, 64);
    __shared__ float pw[4];
    if ((threadIdx.x & 63) == 0) pw[threadIdx.x >> 6] = part;
    __syncthreads();
    if (threadIdx.x == 0)
        atomicAdd(out, -(pw[0] + pw[1] + pw[2] + pw[3]) * (1.0f / 64.0f));
}

// ---------------------------------------------------------------------------
extern "C" void kernel_launch(void* const* d_in, const int* in_sizes, int n_in,
                              void* d_out, int out_size, void* d_ws, size_t ws_size,
                              hipStream_t stream)
{
    const float* feat_s     = (const float*)d_in[0];
    const float* feat_t     = (const float*)d_in[1];
    /* d_in[2] = idx, unused: sample_idx[:,0] already holds it */
    const int*   sample_idx = (const int*)  d_in[3];
    const float* w_s        = (const float*)d_in[4];
    const float* b_s        = (const float*)d_in[5];
    const float* w_t        = (const float*)d_in[6];
    const float* b_t        = (const float*)d_in[7];
    const float* mem_v1     = (const float*)d_in[8];
    const float* mem_v2     = (const float*)d_in[9];
    float* out = (float*)d_out;

    // Workspace layout:
    //   [z: 128 f32 = 512 B]
    //   [v: 2*64*128 f32 = 64 KB]
    //   [ex: 2*64*16385 f32 = 8.39 MB]
    //   [E: 128*100000 f32 = 51.2 MB]  (transposed: E[sb][n])
    char*  ws    = (char*)d_ws;
    float* ws_z  = (float*)ws;
    float* ws_v  = (float*)(ws + 512);
    float* ws_ex = (float*)(ws + 512 + 2 * BATCH * FEAT * sizeof(float));
    float* ws_E  = (float*)(ws + 512 + 2 * BATCH * FEAT * sizeof(float)
                               + (size_t)2 * BATCH * KP1 * sizeof(float));

    // z/out zeroing folded into embed_kernel block 0 (saves 2 graph nodes)
    embed_kernel<<<2 * BATCH, 256, 0, stream>>>(feat_s, feat_t, w_s, b_s, w_t, b_t,
                                                ws_v, ws_z, out);
    gemm_exp_kernel<<<2 * NTILES, 256, 0, stream>>>(mem_v1, mem_v2, ws_v, ws_E);
    gather_z_kernel<<<2 * BATCH * GCH, 256, 0, stream>>>(sample_idx, ws_E, ws_ex, ws_z);
    loss_kernel<<<2 * BATCH * 2, 256, 0, stream>>>(ws_ex, ws_z, out);
}